// Round 1
// baseline (139.785 us; speedup 1.0000x reference)
//
#include <hip/hip_runtime.h>
#include <math.h>

// GLIF forward scan. T=64, B=128, N=2048 (derived at runtime from in_sizes).
// All recurrence math in float64: output is 0/1 spikes with threshold 2e-2,
// one flip = fail. f64 error ~1e-16 vs closest spike margin ~1e-7 => safe.
//
// Round-7: fma-collapsed recurrence. Using y in {0,1}:
//   y=0: v = dv*v + (I - lt)
//   y=1: v = (dv*(1-ga))*v + (I - (lt+rw))
// Precompute dvg = dv*(1-ga) and ltr = lt+rw so the per-step chain is
// cmp -> cndmask -> sub/fma (3 dependent f64 ops) instead of the previous
// cmp -> cndmask -> mul -> mul -> add -> add (~5-6). Reassociation is f64-
// epsilon (~1e-16 rel) vs ~1e-7 spike margin: safe.
// History: r3 4n/thread no-depth -> 48us; r4 1n/thread -> 50us (occupancy
// not the limiter); r5 1n D=8 -> ~26us; r6 2n/thread D=8 prefetch,
// 512 B/wave per VMEM inst (best harness-verified 138.4us total).

typedef float  fx2 __attribute__((ext_vector_type(2)));
typedef double dx2 __attribute__((ext_vector_type(2)));

__device__ __forceinline__ double dsig(double x) {
    return 1.0 / (1.0 + exp(-x));
}

// Precompute kernel: one thread per (t,n) element of icoef; threads with
// i < N additionally compute the per-n constants.
// ws layout (doubles): [0,N) dv | [N,2N) dvg=dv*(1-ga) | [2N,3N) lt
//                      | [3N,4N) ltr=lt+rw | [4N,5N) thr | [5N, 5N+T*N) icoef
__global__ void glif_pre_kernel(const float* __restrict__ alpha,
                                const float* __restrict__ beta,
                                const float* __restrict__ gamma,
                                const float* __restrict__ tau,
                                const float* __restrict__ Vth,
                                const float* __restrict__ leak,
                                const float* __restrict__ reVth,
                                const float* __restrict__ conduct,
                                double* __restrict__ wsd,
                                int N, int TN) {
    int i = blockIdx.x * blockDim.x + threadIdx.x;
    if (i >= TN) return;
    int n = i % N;
    double be = dsig((double)beta[n]);
    double cs = dsig((double)conduct[i]);
    wsd[5 * N + i] = 1.0 - be * (1.0 - cs);  // icoef[t][n]
    if (i < N) {
        double al     = dsig((double)alpha[i]);
        double ga     = dsig((double)gamma[i]);
        double tau_s  = dsig((double)tau[i]);
        double vth_s  = dsig((double)Vth[i]);
        double leak_s = dsig((double)leak[i]);
        double rev_s  = dsig((double)reVth[i]);
        double dv = 1.0 - al * (1.0 - tau_s);   // decay_v
        double lt = (1.0 - al) * leak_s;        // leak_term
        double rw = (1.0 - ga) * rev_s;         // reset_w
        wsd[0 * N + i] = dv;
        wsd[1 * N + i] = dv * (1.0 - ga);       // dvg (y=1 decay)
        wsd[2 * N + i] = lt;
        wsd[3 * N + i] = lt + rw;               // ltr (y=1 subtract term)
        wsd[4 * N + i] = vth_s;                 // thr
    }
}

// Main scan: 2 neurons/thread, T blocked by D=8 with register double-buffer.
__global__ __launch_bounds__(256) void glif_main2_pf_kernel(
        const float* __restrict__ tx,
        const double* __restrict__ wsd,
        float* __restrict__ out,
        int T, int B, int N) {
    constexpr int D = 8;
    const int half = N >> 1;
    const int idx = blockIdx.x * blockDim.x + threadIdx.x;
    if (idx >= B * half) return;
    const int b = idx / half;
    const int n = (idx - b * half) << 1;

    const double dv0  = wsd[0 * N + n],  dv1  = wsd[0 * N + n + 1];
    const double dvg0 = wsd[1 * N + n],  dvg1 = wsd[1 * N + n + 1];
    const double lt0  = wsd[2 * N + n],  lt1  = wsd[2 * N + n + 1];
    const double ltr0 = wsd[3 * N + n],  ltr1 = wsd[3 * N + n + 1];
    const double th0  = wsd[4 * N + n],  th1  = wsd[4 * N + n + 1];

    const size_t bn = (size_t)b * N + n;
    const size_t stride = (size_t)B * N;   // elements between t-slices (x/out)
    const float*  txp = tx + bn;           // fx2 loads (8-byte aligned: n even)
    const double* icp = wsd + 5 * N + n;   // dx2 loads (16-byte aligned)
    float* op = out + bn;

    double v0 = 0.0, v1 = 0.0;
    bool y0 = false, y1 = false;

    const int nblk = T / D;

    fx2 xa[D], xb[D];
    dx2 ica[D], icb[D];

    // Load block 0 (16 independent loads in flight immediately).
#pragma unroll
    for (int j = 0; j < D; ++j) {
        xa[j]  = __builtin_nontemporal_load((const fx2*)(txp + (size_t)j * stride));
        ica[j] = *(const dx2*)(icp + (size_t)j * N);
    }

    for (int blk = 0; blk < nblk; ++blk) {
        const float*  txn = txp + (size_t)D * stride;
        const double* icn = icp + (size_t)D * N;
        const bool more = (blk + 1 < nblk);
        if (more) {
            // Issue next block's loads before touching this block's data:
            // they stay outstanding across the whole compute chain below.
#pragma unroll
            for (int j = 0; j < D; ++j) {
                xb[j]  = __builtin_nontemporal_load((const fx2*)(txn + (size_t)j * stride));
                icb[j] = *(const dx2*)(icn + (size_t)j * N);
            }
        }

#pragma unroll
        for (int j = 0; j < D; ++j) {
            // lane 0: v = a*v + (I - c), a/c selected by previous spike.
            const double I0 = (double)xa[j].x * ica[j].x;
            const double a0 = y0 ? dvg0 : dv0;
            const double c0 = y0 ? ltr0 : lt0;
            v0 = fma(a0, v0, I0 - c0);
            y0 = v0 > th0;
            // lane 1
            const double I1 = (double)xa[j].y * ica[j].y;
            const double a1 = y1 ? dvg1 : dv1;
            const double c1 = y1 ? ltr1 : lt1;
            v1 = fma(a1, v1, I1 - c1);
            y1 = v1 > th1;

            fx2 o;
            o.x = y0 ? 1.0f : 0.0f;
            o.y = y1 ? 1.0f : 0.0f;
            __builtin_nontemporal_store(o, (fx2*)(op + (size_t)j * stride));
        }

        if (more) {
#pragma unroll
            for (int j = 0; j < D; ++j) { xa[j] = xb[j]; ica[j] = icb[j]; }
        }
        txp = txn; icp = icn; op += (size_t)D * stride;
    }

    // Remainder if T % D != 0 (dead for T=64).
    for (int t = nblk * D; t < T; ++t) {
        const fx2 x = *(const fx2*)txp;
        const dx2 ic = *(const dx2*)icp;
        const double I0 = (double)x.x * ic.x;
        const double a0 = y0 ? dvg0 : dv0;
        const double c0 = y0 ? ltr0 : lt0;
        v0 = fma(a0, v0, I0 - c0);
        y0 = v0 > th0;
        const double I1 = (double)x.y * ic.y;
        const double a1 = y1 ? dvg1 : dv1;
        const double c1 = y1 ? ltr1 : lt1;
        v1 = fma(a1, v1, I1 - c1);
        y1 = v1 > th1;
        fx2 o;
        o.x = y0 ? 1.0f : 0.0f;
        o.y = y1 ? 1.0f : 0.0f;
        *(fx2*)op = o;
        txp += stride; icp += N; op += stride;
    }
}

// Fallback (only if ws too small): computes all sigmoids inline per thread,
// 2 neurons/thread. Same f64 expression tree (fma-collapsed form).
__global__ __launch_bounds__(256) void glif_main_inline_kernel(
        const float* __restrict__ tx,
        const float* __restrict__ alpha,
        const float* __restrict__ beta,
        const float* __restrict__ gamma,
        const float* __restrict__ tau,
        const float* __restrict__ Vth,
        const float* __restrict__ leak,
        const float* __restrict__ reVth,
        const float* __restrict__ conduct,
        float* __restrict__ out,
        int T, int B, int N) {
    const int half = N >> 1;
    const int idx = blockIdx.x * blockDim.x + threadIdx.x;
    if (idx >= B * half) return;
    const int b = idx / half;
    const int n = (idx - b * half) << 1;

    const double al0 = dsig((double)alpha[n]), al1 = dsig((double)alpha[n + 1]);
    const double ga0 = dsig((double)gamma[n]), ga1 = dsig((double)gamma[n + 1]);
    const double be0 = dsig((double)beta[n]),  be1 = dsig((double)beta[n + 1]);
    const double ts0 = dsig((double)tau[n]),   ts1 = dsig((double)tau[n + 1]);
    const double th0 = dsig((double)Vth[n]),   th1 = dsig((double)Vth[n + 1]);
    const double ls0 = dsig((double)leak[n]),  ls1 = dsig((double)leak[n + 1]);
    const double rs0 = dsig((double)reVth[n]), rs1 = dsig((double)reVth[n + 1]);
    const double dv0 = 1.0 - al0 * (1.0 - ts0), dv1 = 1.0 - al1 * (1.0 - ts1);
    const double lt0 = (1.0 - al0) * ls0,       lt1 = (1.0 - al1) * ls1;
    const double rw0 = (1.0 - ga0) * rs0,       rw1 = (1.0 - ga1) * rs1;
    const double dvg0 = dv0 * (1.0 - ga0), dvg1 = dv1 * (1.0 - ga1);
    const double ltr0 = lt0 + rw0,         ltr1 = lt1 + rw1;

    double v0 = 0.0, v1 = 0.0;
    bool y0 = false, y1 = false;

    const size_t bn = (size_t)b * N + n;
    const float* txp = tx + bn;
    float* op = out + bn;
    const float* cp = conduct + n;
    const size_t strideTx = (size_t)B * N;

    for (int t = 0; t < T; ++t) {
        const float2 x = *(const float2*)txp;
        const double ic0 = 1.0 - be0 * (1.0 - dsig((double)cp[0]));
        const double ic1 = 1.0 - be1 * (1.0 - dsig((double)cp[1]));

        const double I0 = (double)x.x * ic0;
        const double a0 = y0 ? dvg0 : dv0;
        const double c0 = y0 ? ltr0 : lt0;
        v0 = fma(a0, v0, I0 - c0);
        y0 = v0 > th0;

        const double I1 = (double)x.y * ic1;
        const double a1 = y1 ? dvg1 : dv1;
        const double c1 = y1 ? ltr1 : lt1;
        v1 = fma(a1, v1, I1 - c1);
        y1 = v1 > th1;

        float2 o;
        o.x = y0 ? 1.0f : 0.0f;
        o.y = y1 ? 1.0f : 0.0f;
        *(float2*)op = o;

        txp += strideTx;
        op += strideTx;
        cp += N;
    }
}

extern "C" void kernel_launch(void* const* d_in, const int* in_sizes, int n_in,
                              void* d_out, int out_size, void* d_ws, size_t ws_size,
                              hipStream_t stream) {
    const float* tx      = (const float*)d_in[0];
    const float* alpha   = (const float*)d_in[1];
    const float* beta    = (const float*)d_in[2];
    const float* gamma   = (const float*)d_in[3];
    const float* tau     = (const float*)d_in[4];
    const float* Vth     = (const float*)d_in[5];
    const float* leak    = (const float*)d_in[6];
    const float* reVth   = (const float*)d_in[7];
    const float* conduct = (const float*)d_in[8];
    float* out = (float*)d_out;

    const int N  = in_sizes[1];        // 2048
    const int TN = in_sizes[8];        // T*N = 131072
    const int T  = TN / N;             // 64
    const int B  = in_sizes[0] / TN;   // 128

    const size_t needed = (size_t)(5 * N + TN) * sizeof(double);
    if (ws_size >= needed && (N & 1) == 0) {
        double* wsd = (double*)d_ws;
        const int preBlocks = (TN + 255) / 256;
        glif_pre_kernel<<<preBlocks, 256, 0, stream>>>(
            alpha, beta, gamma, tau, Vth, leak, reVth, conduct, wsd, N, TN);
        const int total = B * (N >> 1);
        glif_main2_pf_kernel<<<(total + 255) / 256, 256, 0, stream>>>(
            tx, wsd, out, T, B, N);
    } else {
        const int total = B * (N >> 1);
        glif_main_inline_kernel<<<(total + 255) / 256, 256, 0, stream>>>(
            tx, alpha, beta, gamma, tau, Vth, leak, reVth, conduct,
            out, T, B, N);
    }
}